// Round 1
// baseline (5996.957 us; speedup 1.0000x reference)
//
#include <hip/hip_runtime.h>
#include <hip/hip_bf16.h>

#define B_ 32
#define T_ 512
#define E_ 256
#define H_ 512
#define L_ 50
#define NBLK 64

typedef __attribute__((ext_vector_type(8))) short short8;
typedef __attribute__((ext_vector_type(4))) float v4f;

__device__ __forceinline__ unsigned short f2bf(float f){
    union { float f; unsigned u; } v; v.f = f;
    unsigned u = v.u;
    u += 0x7fffu + ((u >> 16) & 1u);   // RNE
    return (unsigned short)(u >> 16);
}
__device__ __forceinline__ float sigf(float x){ return 1.0f / (1.0f + expf(-x)); }

__device__ __forceinline__ float qredmax(float v){
    v = fmaxf(v, __shfl_xor(v, 1, 64));
    v = fmaxf(v, __shfl_xor(v, 2, 64));
    v = fmaxf(v, __shfl_xor(v, 4, 64));
    v = fmaxf(v, __shfl_xor(v, 8, 64));
    return v;
}
__device__ __forceinline__ float qredsum(float v){
    v += __shfl_xor(v, 1, 64);
    v += __shfl_xor(v, 2, 64);
    v += __shfl_xor(v, 4, 64);
    v += __shfl_xor(v, 8, 64);
    return v;
}

// ---------------------------------------------------------------- init
__global__ void init_kernel(const float* __restrict__ projW,
                            float* __restrict__ out,
                            unsigned int* __restrict__ cnt,
                            unsigned short* __restrict__ h0,
                            unsigned short* __restrict__ Wt)
{
    const int i = blockIdx.x * 256 + threadIdx.x;   // grid covers 32768
    if (i < T_ + 2) cnt[i] = 0u;
    if (i == 0) out[0] = 0.f;
    if (i < B_ * H_) h0[i] = 0;                     // h_all step 0 = zeros
    if (i < 64 * H_){                               // Wt[c][k] = proj_W[k][c], bf16, pad c>=50 with 0
        const int c = i >> 9;
        const int k = i & 511;
        const float v = (c < L_) ? projW[k * L_ + c] : 0.f;
        Wt[i] = f2bf(v);
    }
}

// ---------------------------------------------------------------- LSTM recurrence (cooperative)
// z^T = W^T * h^T per step. Column permutation within a block: z-col c_local = 4*hc_local + gate,
// so D-layout (row = quad*4+reg) puts gates i,j,f,o of one (b,hc) into acc[0..3] of one lane.
__global__ void __launch_bounds__(256, 1) lstm_kernel(
    const int* __restrict__ q, const int* __restrict__ lengths,
    const float* __restrict__ we, const float* __restrict__ lstmW,
    const float* __restrict__ lstmB,
    unsigned short* __restrict__ h_all, unsigned int* __restrict__ cnt)
{
    const int tid  = threadIdx.x;
    const int wv   = tid >> 6;
    const int lane = tid & 63;
    const int mt = wv & 1, nt = wv >> 1;
    const int l15 = lane & 15, quad = lane >> 4;
    const int blk = blockIdx.x;

    // ---- A-operand mapping (lane&15 = m = z-col within m-tile; k = quad*8 + j)
    const int hcA  = blk * 8 + mt * 4 + (l15 >> 2);
    const int gA   = l15 & 3;
    const int colA = gA * H_ + hcA;                  // column in original lstm_W [768][2048]

    short8 AW[8], AH[16];
#pragma unroll
    for (int kc = 0; kc < 8; ++kc){                  // x-part rows 0..255
        short8 f;
#pragma unroll
        for (int j = 0; j < 8; ++j){
            const int r = kc * 32 + quad * 8 + j;
            f[j] = (short)f2bf(lstmW[(size_t)r * 2048 + colA]);
        }
        AW[kc] = f;
    }
#pragma unroll
    for (int kc = 0; kc < 16; ++kc){                 // h-part rows 256..767
        short8 f;
#pragma unroll
        for (int j = 0; j < 8; ++j){
            const int r = E_ + kc * 32 + quad * 8 + j;
            f[j] = (short)f2bf(lstmW[(size_t)r * 2048 + colA]);
        }
        AH[kc] = f;
    }

    // ---- epilogue / B-operand mapping (lane&15 = n = batch; D row quad*4+reg -> hc=quad, gate=reg)
    const int bE  = nt * 16 + l15;
    const int hcE = blk * 8 + mt * 4 + quad;
    float bias4[4];
#pragma unroll
    for (int g = 0; g < 4; ++g) bias4[g] = lstmB[g * H_ + hcE];
    const int lenb = lengths[bE];

    float c_state = 0.f, h_prev = 0.f;

    // embedding prefetch registers (raw fp32) for current t
    v4f er[16];
    {
        const int qv = q[bE * T_];
        const v4f* wp = (const v4f*)(we + (size_t)qv * E_);
#pragma unroll
        for (int kc = 0; kc < 8; ++kc){
            er[kc * 2]     = wp[kc * 8 + quad * 2];
            er[kc * 2 + 1] = wp[kc * 8 + quad * 2 + 1];
        }
    }

    for (int t = 0; t < T_; ++t){
        v4f acc = { bias4[0], bias4[1], bias4[2], bias4[3] };

        // x-part (independent of h) — overlaps the spin below
#pragma unroll
        for (int kc = 0; kc < 8; ++kc){
            short8 eb;
#pragma unroll
            for (int j = 0; j < 4; ++j) eb[j]     = (short)f2bf(er[kc * 2][j]);
#pragma unroll
            for (int j = 0; j < 4; ++j) eb[4 + j] = (short)f2bf(er[kc * 2 + 1][j]);
            acc = __builtin_amdgcn_mfma_f32_16x16x32_bf16(AW[kc], eb, acc, 0, 0, 0);
        }

        if (t > 0){
            if (tid == 0){
                int guard = 0;
                while (__hip_atomic_load(&cnt[t], __ATOMIC_RELAXED, __HIP_MEMORY_SCOPE_AGENT) < NBLK){
                    __builtin_amdgcn_s_sleep(2);
                    if (++guard > (1 << 22)) break;   // safety valve, never hit in practice
                }
            }
            __syncthreads();
            __builtin_amdgcn_fence(__ATOMIC_ACQUIRE, "agent");
        }

        // h-part
        const unsigned short* hrow = h_all + (size_t)t * (B_ * H_) + (size_t)bE * H_;
#pragma unroll
        for (int kc = 0; kc < 16; ++kc){
            const short8 hb = *(const short8*)(hrow + kc * 32 + quad * 8);
            acc = __builtin_amdgcn_mfma_f32_16x16x32_bf16(AH[kc], hb, acc, 0, 0, 0);
        }

        // gates: i=acc[0], j=acc[1], f=acc[2], o=acc[3]
        const float gi = acc[0], gj = acc[1], gf = acc[2], go = acc[3];
        const float c_new = c_state * sigf(gf + 1.0f) + sigf(gi) * tanhf(gj);
        const float h_new = tanhf(c_new) * sigf(go);
        const bool msk = (t < lenb);
        c_state = msk ? c_new : c_state;
        const float h2 = msk ? h_new : h_prev;       // dynamic_rnn state copy-through
        h_prev = h2;
        h_all[(size_t)(t + 1) * (B_ * H_) + (size_t)bE * H_ + hcE] = f2bf(h2);

        __builtin_amdgcn_fence(__ATOMIC_RELEASE, "agent");
        __syncthreads();
        if (tid == 0)
            __hip_atomic_fetch_add(&cnt[t + 1], 1u, __ATOMIC_RELAXED, __HIP_MEMORY_SCOPE_AGENT);

        // prefetch next step's embeddings AFTER the release fence (not drained by it)
        if (t + 1 < T_){
            const int qv = q[bE * T_ + t + 1];
            const v4f* wp = (const v4f*)(we + (size_t)qv * E_);
#pragma unroll
            for (int kc = 0; kc < 8; ++kc){
                er[kc * 2]     = wp[kc * 8 + quad * 2];
                er[kc * 2 + 1] = wp[kc * 8 + quad * 2 + 1];
            }
        }
    }
}

// ---------------------------------------------------------------- projection + relu + log-softmax + xent
__global__ void __launch_bounds__(256) loss_kernel(
    const int* __restrict__ a, const int* __restrict__ lengths,
    const float* __restrict__ projB,
    const unsigned short* __restrict__ h_all,
    const unsigned short* __restrict__ Wt,
    float* __restrict__ out)
{
    const int tid = threadIdx.x;
    const int wv = tid >> 6, lane = tid & 63;
    const int l15 = lane & 15, quad = lane >> 4;
    const int wgid = blockIdx.x * 4 + wv;            // 0..1023
    const int row0 = wgid * 16;

    // A-frags: h rows (row = flat b*512 + t), stored at h_all[t+1][b][:]
    const int rowA = row0 + l15;
    const int bA = rowA >> 9, tA = rowA & 511;
    const unsigned short* hrow = h_all + ((size_t)(tA + 1) * B_ + bA) * H_;

    v4f acc[4] = { {0,0,0,0}, {0,0,0,0}, {0,0,0,0}, {0,0,0,0} };
#pragma unroll
    for (int kc = 0; kc < 16; ++kc){
        const short8 af = *(const short8*)(hrow + kc * 32 + quad * 8);
#pragma unroll
        for (int ntl = 0; ntl < 4; ++ntl){
            const short8 bf = *(const short8*)(Wt + (size_t)(ntl * 16 + l15) * H_ + kc * 32 + quad * 8);
            acc[ntl] = __builtin_amdgcn_mfma_f32_16x16x32_bf16(af, bf, acc[ntl], 0, 0, 0);
        }
    }

    float pb[4]; bool cv[4];
#pragma unroll
    for (int ntl = 0; ntl < 4; ++ntl){
        const int c = ntl * 16 + l15;
        cv[ntl] = (c < L_);
        pb[ntl] = cv[ntl] ? projB[c] : 0.f;
    }

#pragma unroll
    for (int r = 0; r < 4; ++r){
        const int row = row0 + quad * 4 + r;
        const int b = row >> 9, t = row & 511;
        const int len = lengths[b];
        const bool valid = (t < len);

        float lv[4];
#pragma unroll
        for (int ntl = 0; ntl < 4; ++ntl)
            lv[ntl] = fmaxf(acc[ntl][r] + pb[ntl], 0.f);   // relu(logits)

        float mx = -1e30f;
#pragma unroll
        for (int ntl = 0; ntl < 4; ++ntl) if (cv[ntl]) mx = fmaxf(mx, lv[ntl]);
        mx = qredmax(mx);
        float se = 0.f;
#pragma unroll
        for (int ntl = 0; ntl < 4; ++ntl) if (cv[ntl]) se += expf(lv[ntl] - mx);
        se = qredsum(se);
        const int lbl = a[row];
        float cand = 0.f;
#pragma unroll
        for (int ntl = 0; ntl < 4; ++ntl) if (ntl * 16 + l15 == lbl) cand = lv[ntl];
        const float llbl = qredsum(cand);

        if (valid && l15 == 0){
            const float xent = logf(se) + mx - llbl;      // -log_softmax[label]
            atomicAdd(out, xent / ((float)len * 32.0f));
        }
    }
}

// ---------------------------------------------------------------- launch
extern "C" void kernel_launch(void* const* d_in, const int* in_sizes, int n_in,
                              void* d_out, int out_size, void* d_ws, size_t ws_size,
                              hipStream_t stream)
{
    const int*   q   = (const int*)d_in[0];
    const int*   a   = (const int*)d_in[1];
    const int*   len = (const int*)d_in[2];
    const float* we  = (const float*)d_in[3];
    const float* lW  = (const float*)d_in[4];
    const float* lB  = (const float*)d_in[5];
    const float* pW  = (const float*)d_in[6];
    const float* pB  = (const float*)d_in[7];
    float* out = (float*)d_out;

    unsigned char* ws = (unsigned char*)d_ws;
    unsigned int*   cnt   = (unsigned int*)ws;                                   // 4 KiB
    unsigned short* h_all = (unsigned short*)(ws + 4096);                        // 513*32*512*2 B
    unsigned short* Wt    = (unsigned short*)(ws + 4096 + (size_t)(T_ + 1) * B_ * H_ * 2); // 64*512*2 B

    init_kernel<<<dim3(128), dim3(256), 0, stream>>>(pW, out, cnt, h_all, Wt);

    {
        const int* q_ = q; const int* len_ = len; const float* we_ = we;
        const float* lW_ = lW; const float* lB_ = lB;
        unsigned short* h_ = h_all; unsigned int* c_ = cnt;
        void* args[] = { (void*)&q_, (void*)&len_, (void*)&we_, (void*)&lW_,
                         (void*)&lB_, (void*)&h_, (void*)&c_ };
        hipLaunchCooperativeKernel((void*)lstm_kernel, dim3(NBLK), dim3(256),
                                   args, 0, stream);
    }

    loss_kernel<<<dim3(256), dim3(256), 0, stream>>>(a, len, pB, h_all, Wt, out);
}